// Round 5
// baseline (188.542 us; speedup 1.0000x reference)
//
#include <hip/hip_runtime.h>
#include <stdint.h>

// Problem constants (from reference)
#define BATCH 8192
#define FEAT 768
#define NCVX 32768            // BATCH * MULTIPLE_CONVEX
#define NOUT (BATCH + NCVX)   // 40960
#define UNSEEN 150

// Native 4-float vector (HIP's float4 is a class; the nontemporal builtin
// needs a true vector-of-float type).
typedef float vf4 __attribute__((ext_vector_type(4)));

// Output is FLOAT32: flat [NOUT*FEAT] z_out followed by [NOUT] labels-as-f32.
// One thread per 32B segment = 8 f32 (two 16B loads/stores, contiguous per
// lane -> a 64-lane wave covers 2KB contiguous; fully coalesced).
#define ROW_SEGS (FEAT / 8)                            // 96
constexpr int COPY_SEGS = BATCH * ROW_SEGS;            // 786432
constexpr int CVX_SEGS  = NCVX  * ROW_SEGS;            // 3145728
constexpr int LAB_SEGS  = NOUT / 8;                    // 5120
constexpr int TOTAL_SEGS = COPY_SEGS + CVX_SEGS + LAB_SEGS;   // 3937280

__global__ __launch_bounds__(256) void ConvexSampler_39006892982339_kernel(
    const float* __restrict__ z,       // f32 [BATCH, FEAT]
    const int*   __restrict__ labels,  // i32 [BATCH]
    const int*   __restrict__ idx_i,   // i32 [NCVX]
    const int*   __restrict__ idx_j,   // i32 [NCVX]
    const float* __restrict__ s,       // f32 [NCVX]
    float*       __restrict__ out)     // f32 [NOUT*FEAT + NOUT]
{
    int t = blockIdx.x * 256 + threadIdx.x;
    if (t >= TOTAL_SEGS) return;

    if (t < COPY_SEGS) {
        // straight copy z -> out[0 : BATCH*FEAT]; nt stores keep z in L2
        const vf4* zp = (const vf4*)z + 2 * (size_t)t;
        vf4 a = zp[0];
        vf4 b = zp[1];
        vf4* op = (vf4*)out + 2 * (size_t)t;
        __builtin_nontemporal_store(a, op);
        __builtin_nontemporal_store(b, op + 1);
    } else if (t < COPY_SEGS + CVX_SEGS) {
        int c   = t - COPY_SEGS;
        int row = c / ROW_SEGS;                  // magic-mul, cheap
        int col = c - row * ROW_SEGS;            // 8-float segment within row
        float sw  = s[row];
        float sw1 = 1.0f - sw;
        const vf4* ap = (const vf4*)(z + (size_t)idx_i[row] * FEAT) + 2 * col;
        const vf4* bp = (const vf4*)(z + (size_t)idx_j[row] * FEAT) + 2 * col;
        vf4 a0 = ap[0], a1 = ap[1];
        vf4 b0 = bp[0], b1 = bp[1];
        vf4 r0 = sw * a0 + sw1 * b0;   // vector ops on ext_vector_type
        vf4 r1 = sw * a1 + sw1 * b1;
        // convex rows land right after the copied z rows; out segment == t
        vf4* op = (vf4*)out + 2 * (size_t)t;
        __builtin_nontemporal_store(r0, op);
        __builtin_nontemporal_store(r1, op + 1);
    } else {
        // labels region: out[NOUT*FEAT + k] = (float)(k < BATCH ? labels[k] : UNSEEN)
        int c    = t - (COPY_SEGS + CVX_SEGS);
        int base = c * 8;
        vf4 r0, r1;
        r0.x = (float)(base + 0 < BATCH ? labels[base + 0] : UNSEEN);
        r0.y = (float)(base + 1 < BATCH ? labels[base + 1] : UNSEEN);
        r0.z = (float)(base + 2 < BATCH ? labels[base + 2] : UNSEEN);
        r0.w = (float)(base + 3 < BATCH ? labels[base + 3] : UNSEEN);
        r1.x = (float)(base + 4 < BATCH ? labels[base + 4] : UNSEEN);
        r1.y = (float)(base + 5 < BATCH ? labels[base + 5] : UNSEEN);
        r1.z = (float)(base + 6 < BATCH ? labels[base + 6] : UNSEEN);
        r1.w = (float)(base + 7 < BATCH ? labels[base + 7] : UNSEEN);
        vf4* op = (vf4*)(out + (size_t)NOUT * FEAT) + 2 * (size_t)c;
        __builtin_nontemporal_store(r0, op);
        __builtin_nontemporal_store(r1, op + 1);
    }
}

extern "C" void kernel_launch(void* const* d_in, const int* in_sizes, int n_in,
                              void* d_out, int out_size, void* d_ws, size_t ws_size,
                              hipStream_t stream) {
    const float* z      = (const float*)d_in[0];
    const int*   labels = (const int*)d_in[1];
    const int*   idx_i  = (const int*)d_in[2];
    const int*   idx_j  = (const int*)d_in[3];
    const float* s      = (const float*)d_in[4];
    float*       out    = (float*)d_out;

    int blocks = (TOTAL_SEGS + 255) / 256;
    ConvexSampler_39006892982339_kernel<<<blocks, 256, 0, stream>>>(
        z, labels, idx_i, idx_j, s, out);
}

// Round 6
// 173.683 us; speedup vs baseline: 1.0855x; 1.0855x over previous
//
#include <hip/hip_runtime.h>
#include <stdint.h>

// Problem constants (from reference)
#define BATCH 8192
#define FEAT 768
#define NCVX 32768            // BATCH * MULTIPLE_CONVEX
#define NOUT (BATCH + NCVX)   // 40960
#define UNSEEN 150

// Native 4-float vector (HIP's float4 is a class; nontemporal builtin needs
// a true vector-of-float type).
typedef float vf4 __attribute__((ext_vector_type(4)));

// Structure: one WAVE per output row (768 f32 = 3 rounds x 64 lanes x float4;
// every load/store instruction is a dense 1KB-per-wave access). Block = 256
// threads = 4 rows. Copy/convex boundary (row 8192) falls exactly at block
// 2048 -> branch is block-uniform, no divergence. idx/s loads are one
// broadcast address per wave. nt stores: output is write-once, keep L2 free
// for the z gather working set (25 MB vs 4 MB/XCD L2).
constexpr int ROWS_PER_BLOCK = 4;
constexpr int ROW_BLOCKS = NOUT / ROWS_PER_BLOCK;            // 10240
constexpr int LAB_BLOCKS = NOUT / 1024;                      // 40 (256 thr x 4 f32)
constexpr int TOTAL_BLOCKS = ROW_BLOCKS + LAB_BLOCKS;        // 10280

__global__ __launch_bounds__(256) void ConvexSampler_39006892982339_kernel(
    const float* __restrict__ z,       // f32 [BATCH, FEAT]
    const int*   __restrict__ labels,  // i32 [BATCH]
    const int*   __restrict__ idx_i,   // i32 [NCVX]
    const int*   __restrict__ idx_j,   // i32 [NCVX]
    const float* __restrict__ s,       // f32 [NCVX]
    float*       __restrict__ out)     // f32 [NOUT*FEAT + NOUT]
{
    int blk = blockIdx.x;
    if (blk < ROW_BLOCKS) {
        int wave = threadIdx.x >> 6;
        int lane = threadIdx.x & 63;
        int row  = blk * ROWS_PER_BLOCK + wave;          // 0..NOUT-1
        vf4* op = (vf4*)(out + (size_t)row * FEAT);
        if (row < BATCH) {
            // copy region: out[row] = z[row]
            const vf4* zp = (const vf4*)(z + (size_t)row * FEAT);
#pragma unroll
            for (int j = 0; j < 3; ++j) {
                vf4 v = zp[j * 64 + lane];
                __builtin_nontemporal_store(v, op + j * 64 + lane);
            }
        } else {
            // convex region: out[row] = s[c]*z[idx_i[c]] + (1-s[c])*z[idx_j[c]]
            int c = row - BATCH;
            float sw  = s[c];
            float sw1 = 1.0f - sw;
            const vf4* ap = (const vf4*)(z + (size_t)idx_i[c] * FEAT);
            const vf4* bp = (const vf4*)(z + (size_t)idx_j[c] * FEAT);
            // issue all 6 gather loads before the fmas (ILP for latency hiding)
            vf4 a0 = ap[0 * 64 + lane];
            vf4 a1 = ap[1 * 64 + lane];
            vf4 a2 = ap[2 * 64 + lane];
            vf4 b0 = bp[0 * 64 + lane];
            vf4 b1 = bp[1 * 64 + lane];
            vf4 b2 = bp[2 * 64 + lane];
            vf4 r0 = sw * a0 + sw1 * b0;
            vf4 r1 = sw * a1 + sw1 * b1;
            vf4 r2 = sw * a2 + sw1 * b2;
            __builtin_nontemporal_store(r0, op + 0 * 64 + lane);
            __builtin_nontemporal_store(r1, op + 1 * 64 + lane);
            __builtin_nontemporal_store(r2, op + 2 * 64 + lane);
        }
    } else {
        // labels region: out[NOUT*FEAT + k] = (float)(k < BATCH ? labels[k] : UNSEEN)
        int c4   = (blk - ROW_BLOCKS) * 256 + threadIdx.x;   // float4 index
        int base = c4 * 4;                                   // f32 index; BATCH%4==0
        vf4 r;
        if (base < BATCH) {
            r.x = (float)labels[base + 0];
            r.y = (float)labels[base + 1];
            r.z = (float)labels[base + 2];
            r.w = (float)labels[base + 3];
        } else {
            r = (vf4)((float)UNSEEN);
        }
        __builtin_nontemporal_store(r, (vf4*)(out + (size_t)NOUT * FEAT) + c4);
    }
}

extern "C" void kernel_launch(void* const* d_in, const int* in_sizes, int n_in,
                              void* d_out, int out_size, void* d_ws, size_t ws_size,
                              hipStream_t stream) {
    const float* z      = (const float*)d_in[0];
    const int*   labels = (const int*)d_in[1];
    const int*   idx_i  = (const int*)d_in[2];
    const int*   idx_j  = (const int*)d_in[3];
    const float* s      = (const float*)d_in[4];
    float*       out    = (float*)d_out;

    ConvexSampler_39006892982339_kernel<<<TOTAL_BLOCKS, 256, 0, stream>>>(
        z, labels, idx_i, idx_j, s, out);
}